// Round 7
// baseline (519.012 us; speedup 1.0000x reference)
//
#include <hip/hip_runtime.h>
#include <hip/hip_bf16.h>
#include <math.h>
#include <stdint.h>

#define B_BATCH   1024
#define D_DIM     512
#define C_CLASSES 100000
#define BM        128
#define BN        128
#define BK        64
#define KITERS    (D_DIM / BK)                    // 8
#define MTILES    (B_BATCH / BM)                  // 8
#define NTILES    ((C_CLASSES + BN - 1) / BN)     // 782
#define NGROUPS   98                              // ceil(782/8)
#define GRID_G    (8 * 8 * NGROUPS)               // 6272 blocks (16 early-exit)
#define LOG2E     1.44269504088896340736f
#define COSM      0.87758256189037276f            // cos(0.5)
#define SINM      0.47942553860420301f            // sin(0.5)
#define NEG_LOG_EPS 69.07755278982137f            // -ln(1e-30)

typedef short bf16x8 __attribute__((ext_vector_type(8)));
typedef float f32x4  __attribute__((ext_vector_type(4)));

static __device__ __forceinline__ unsigned short f2bf(float f) {
    unsigned int u = __builtin_bit_cast(unsigned int, f);
    u += 0x7fffu + ((u >> 16) & 1u);              // round-to-nearest-even
    return (unsigned short)(u >> 16);
}

// async 16B/lane global -> LDS (LDS dest = wave-uniform base + lane*16)
static __device__ __forceinline__ void gld16(const unsigned short* g, unsigned short* l) {
    __builtin_amdgcn_global_load_lds(
        (const __attribute__((address_space(1))) unsigned int*)g,
        (__attribute__((address_space(3))) unsigned int*)l, 16, 0, 0);
}

// ---------------- kernel 1: normalize embeddings -> bf16 A [1024 x 512] ---
__global__ __launch_bounds__(256) void norm_embed(const float* __restrict__ E,
                                                  unsigned short* __restrict__ Abf) {
    const int b = blockIdx.x;
    const int t = threadIdx.x;
    float2 v = ((const float2*)(E + (size_t)b * D_DIM))[t];
    float ss = v.x * v.x + v.y * v.y;
    #pragma unroll
    for (int off = 1; off < 64; off <<= 1) ss += __shfl_xor(ss, off);
    __shared__ float ws4[4];
    if ((t & 63) == 0) ws4[t >> 6] = ss;
    __syncthreads();
    float inv = rsqrtf(ws4[0] + ws4[1] + ws4[2] + ws4[3]);
    unsigned int packed = (unsigned int)f2bf(v.x * inv) |
                          ((unsigned int)f2bf(v.y * inv) << 16);
    ((unsigned int*)Abf)[(size_t)b * (D_DIM / 2) + t] = packed;
}

// ---------------- kernel 1b: normalize weights -> bf16 [C x 512] ----------
// 2 rows per wave: 4 independent float4 loads in flight + interleaved
// reductions (deeper MLP than 1 row/wave). 12500 blocks x 8 rows = 100000.
__global__ __launch_bounds__(256) void norm_weight(const float* __restrict__ W,
                                                   unsigned short* __restrict__ Wbf) {
    const int wave = threadIdx.x >> 6;
    const int lane = threadIdx.x & 63;
    const int row0 = blockIdx.x * 8 + wave * 2;
    const int row1 = row0 + 1;
    const float4* s0 = (const float4*)(W + (size_t)row0 * D_DIM);
    const float4* s1 = (const float4*)(W + (size_t)row1 * D_DIM);
    float4 a0 = s0[lane];
    float4 a1 = s0[lane + 64];
    float4 b0 = s1[lane];
    float4 b1 = s1[lane + 64];
    float sa = a0.x*a0.x + a0.y*a0.y + a0.z*a0.z + a0.w*a0.w
             + a1.x*a1.x + a1.y*a1.y + a1.z*a1.z + a1.w*a1.w;
    float sb = b0.x*b0.x + b0.y*b0.y + b0.z*b0.z + b0.w*b0.w
             + b1.x*b1.x + b1.y*b1.y + b1.z*b1.z + b1.w*b1.w;
    #pragma unroll
    for (int off = 1; off < 64; off <<= 1) {
        sa += __shfl_xor(sa, off);
        sb += __shfl_xor(sb, off);
    }
    float ia = rsqrtf(sa), ib = rsqrtf(sb);
    ushort4 oa0, oa1, ob0, ob1;
    oa0.x = f2bf(a0.x*ia); oa0.y = f2bf(a0.y*ia); oa0.z = f2bf(a0.z*ia); oa0.w = f2bf(a0.w*ia);
    oa1.x = f2bf(a1.x*ia); oa1.y = f2bf(a1.y*ia); oa1.z = f2bf(a1.z*ia); oa1.w = f2bf(a1.w*ia);
    ob0.x = f2bf(b0.x*ib); ob0.y = f2bf(b0.y*ib); ob0.z = f2bf(b0.z*ib); ob0.w = f2bf(b0.w*ib);
    ob1.x = f2bf(b1.x*ib); ob1.y = f2bf(b1.y*ib); ob1.z = f2bf(b1.z*ib); ob1.w = f2bf(b1.w*ib);
    ushort4* d0 = (ushort4*)(Wbf + (size_t)row0 * D_DIM);
    ushort4* d1 = (ushort4*)(Wbf + (size_t)row1 * D_DIM);
    d0[lane] = oa0; d0[lane + 64] = oa1;
    d1[lane] = ob0; d1[lane + 64] = ob1;
}

// epilogue per-element: clip, ArcFace margin (identity form, no libm),
// returns exp(s - 64)
static __device__ __forceinline__ float epi_term(float accv, int col, int lab,
                                                 float* __restrict__ st, int srow) {
    float c = fminf(1.f, fmaxf(-1.f, accv));
    if (col >= C_CLASSES) return 0.f;
    float s = c * 64.0f;
    if (col == lab) {
        float sn = sqrtf(fmaxf(0.f, 1.f - c * c));
        float nm = c * COSM - sn * SINM;          // cos(theta + m)
        if (c < -COSM) nm = -1.f;                 // theta + m > pi
        s = nm * 64.0f;
        st[srow] = s;                             // unique writer across grid
    }
    return exp2f((s - 64.0f) * LOG2E);
}

// ---------------- kernel 2: bf16 GEMM + margin + partial softmax ----------
// BK=64 (8 iters, half the drain barriers of round 6) + XOR-swizzled LDS:
// row r's 16-byte unit u holds logical k-group u^(r&7), so a fragment read
// (16 lanes, 16 rows) touches all 8 bank groups -> 2-way aliasing = free
// (round 6: only 2 groups -> 8-way conflict, 1.28e7 SQ_LDS_BANK_CONFLICT).
// Staging keeps gld16 contiguity: the swizzle only changes each lane's
// GLOBAL source column, LDS dest stays base + lane*16.
// XCD-colocating 1D grid (round 5): FETCH 404 -> 54 MB.
__global__ __launch_bounds__(256) void gemm_cos(const unsigned short* __restrict__ Abf,
                                                const unsigned short* __restrict__ Wbf,
                                                const int* __restrict__ labels,
                                                float* __restrict__ st,
                                                float* __restrict__ partial) {
    __shared__ unsigned short As[BM * BK];   // 16 KiB
    __shared__ unsigned short Bs[BN * BK];   // 16 KiB
    __shared__ float rowSum[BM];
    __shared__ int   labs[BM];

    const int id = blockIdx.x;
    const int x  = id & 7;          // XCD slot
    const int s  = id >> 3;         // sequence on this XCD
    const int mt = s & 7;           // m-tile
    const int y  = x + 8 * (s >> 3);// n-tile: 8 consecutive s share y per XCD
    if (y >= NTILES) return;
    const int m0 = mt * BM;
    const int n0 = y * BN;

    const int tid = threadIdx.x;
    if (tid < BM) { labs[tid] = labels[m0 + tid]; rowSum[tid] = 0.f; }

    const int lane = tid & 63;
    const int wave = tid >> 6;
    const int wm = wave & 1, wn = wave >> 1;
    const int l15 = lane & 15, quad = lane >> 4;

    // staging: chunk c = tile rows [8c, 8c+8) (1 KiB); wave w stages chunks
    // 4w..4w+3 of A and of B. Lane i -> row 8c + (i>>3), 16B unit (i&7);
    // swizzle: that unit's GLOBAL k-group is (i&7) ^ (i>>3).
    const int rsub = lane >> 3;                 // 0..7
    const int cgsw = ((lane & 7) ^ rsub) * 8;   // swizzled source column
    const int c0 = wave * 4;
    const unsigned short* gA0 = Abf + (size_t)(m0 + (c0 + 0) * 8 + rsub) * D_DIM + cgsw;
    const unsigned short* gA1 = Abf + (size_t)(m0 + (c0 + 1) * 8 + rsub) * D_DIM + cgsw;
    const unsigned short* gA2 = Abf + (size_t)(m0 + (c0 + 2) * 8 + rsub) * D_DIM + cgsw;
    const unsigned short* gA3 = Abf + (size_t)(m0 + (c0 + 3) * 8 + rsub) * D_DIM + cgsw;
    const int bRa = min(n0 + (c0 + 0) * 8 + rsub, C_CLASSES - 1);
    const int bRb = min(n0 + (c0 + 1) * 8 + rsub, C_CLASSES - 1);
    const int bRc = min(n0 + (c0 + 2) * 8 + rsub, C_CLASSES - 1);
    const int bRd = min(n0 + (c0 + 3) * 8 + rsub, C_CLASSES - 1);
    const unsigned short* gB0 = Wbf + (size_t)bRa * D_DIM + cgsw;
    const unsigned short* gB1 = Wbf + (size_t)bRb * D_DIM + cgsw;
    const unsigned short* gB2 = Wbf + (size_t)bRc * D_DIM + cgsw;
    const unsigned short* gB3 = Wbf + (size_t)bRd * D_DIM + cgsw;
    unsigned short* lA0 = &As[(c0 + 0) * 512];
    unsigned short* lA1 = &As[(c0 + 1) * 512];
    unsigned short* lA2 = &As[(c0 + 2) * 512];
    unsigned short* lA3 = &As[(c0 + 3) * 512];
    unsigned short* lB0 = &Bs[(c0 + 0) * 512];
    unsigned short* lB1 = &Bs[(c0 + 1) * 512];
    unsigned short* lB2 = &Bs[(c0 + 2) * 512];
    unsigned short* lB3 = &Bs[(c0 + 3) * 512];

    const f32x4 z = (f32x4){0.f, 0.f, 0.f, 0.f};
    f32x4 a00 = z, a01 = z, a02 = z, a03 = z;
    f32x4 a10 = z, a11 = z, a12 = z, a13 = z;
    f32x4 a20 = z, a21 = z, a22 = z, a23 = z;
    f32x4 a30 = z, a31 = z, a32 = z, a33 = z;

    // fragment offsets: row r, kstep s in {0,1}: elem = r*64 + ((s*4+quad)^(r&7))*8
    const int axr = l15 & 7;
    const int arow = (wm * 64 + l15) * BK;
    const int brow = (wn * 64 + l15) * BK;
    const int u0 = ((quad)     ^ axr) * 8;      // kstep 0 unit offset
    const int u1 = ((4 + quad) ^ axr) * 8;      // kstep 1 unit offset

    for (int kk = 0; kk < KITERS; ++kk) {
        __syncthreads();                     // prior frag reads done
        gld16(gA0, lA0); gld16(gA1, lA1); gld16(gA2, lA2); gld16(gA3, lA3);
        gld16(gB0, lB0); gld16(gB1, lB1); gld16(gB2, lB2); gld16(gB3, lB3);
        gA0 += BK; gA1 += BK; gA2 += BK; gA3 += BK;
        gB0 += BK; gB1 += BK; gB2 += BK; gB3 += BK;
        __syncthreads();                     // loads visible

        // ---- kstep 0 (k = kk*64 .. +31) ----
        bf16x8 af0 = *(const bf16x8*)&As[arow + u0];
        bf16x8 af1 = *(const bf16x8*)&As[arow + 16 * BK + u0];
        bf16x8 af2 = *(const bf16x8*)&As[arow + 32 * BK + u0];
        bf16x8 af3 = *(const bf16x8*)&As[arow + 48 * BK + u0];
        bf16x8 bf0 = *(const bf16x8*)&Bs[brow + u0];
        bf16x8 bf1 = *(const bf16x8*)&Bs[brow + 16 * BK + u0];
        bf16x8 bf2 = *(const bf16x8*)&Bs[brow + 32 * BK + u0];
        bf16x8 bf3 = *(const bf16x8*)&Bs[brow + 48 * BK + u0];

        a00 = __builtin_amdgcn_mfma_f32_16x16x32_bf16(af0, bf0, a00, 0, 0, 0);
        a01 = __builtin_amdgcn_mfma_f32_16x16x32_bf16(af0, bf1, a01, 0, 0, 0);
        a02 = __builtin_amdgcn_mfma_f32_16x16x32_bf16(af0, bf2, a02, 0, 0, 0);
        a03 = __builtin_amdgcn_mfma_f32_16x16x32_bf16(af0, bf3, a03, 0, 0, 0);
        a10 = __builtin_amdgcn_mfma_f32_16x16x32_bf16(af1, bf0, a10, 0, 0, 0);
        a11 = __builtin_amdgcn_mfma_f32_16x16x32_bf16(af1, bf1, a11, 0, 0, 0);
        a12 = __builtin_amdgcn_mfma_f32_16x16x32_bf16(af1, bf2, a12, 0, 0, 0);
        a13 = __builtin_amdgcn_mfma_f32_16x16x32_bf16(af1, bf3, a13, 0, 0, 0);
        a20 = __builtin_amdgcn_mfma_f32_16x16x32_bf16(af2, bf0, a20, 0, 0, 0);
        a21 = __builtin_amdgcn_mfma_f32_16x16x32_bf16(af2, bf1, a21, 0, 0, 0);
        a22 = __builtin_amdgcn_mfma_f32_16x16x32_bf16(af2, bf2, a22, 0, 0, 0);
        a23 = __builtin_amdgcn_mfma_f32_16x16x32_bf16(af2, bf3, a23, 0, 0, 0);
        a30 = __builtin_amdgcn_mfma_f32_16x16x32_bf16(af3, bf0, a30, 0, 0, 0);
        a31 = __builtin_amdgcn_mfma_f32_16x16x32_bf16(af3, bf1, a31, 0, 0, 0);
        a32 = __builtin_amdgcn_mfma_f32_16x16x32_bf16(af3, bf2, a32, 0, 0, 0);
        a33 = __builtin_amdgcn_mfma_f32_16x16x32_bf16(af3, bf3, a33, 0, 0, 0);

        // ---- kstep 1 (k = kk*64+32 .. +63) ----
        af0 = *(const bf16x8*)&As[arow + u1];
        af1 = *(const bf16x8*)&As[arow + 16 * BK + u1];
        af2 = *(const bf16x8*)&As[arow + 32 * BK + u1];
        af3 = *(const bf16x8*)&As[arow + 48 * BK + u1];
        bf0 = *(const bf16x8*)&Bs[brow + u1];
        bf1 = *(const bf16x8*)&Bs[brow + 16 * BK + u1];
        bf2 = *(const bf16x8*)&Bs[brow + 32 * BK + u1];
        bf3 = *(const bf16x8*)&Bs[brow + 48 * BK + u1];

        a00 = __builtin_amdgcn_mfma_f32_16x16x32_bf16(af0, bf0, a00, 0, 0, 0);
        a01 = __builtin_amdgcn_mfma_f32_16x16x32_bf16(af0, bf1, a01, 0, 0, 0);
        a02 = __builtin_amdgcn_mfma_f32_16x16x32_bf16(af0, bf2, a02, 0, 0, 0);
        a03 = __builtin_amdgcn_mfma_f32_16x16x32_bf16(af0, bf3, a03, 0, 0, 0);
        a10 = __builtin_amdgcn_mfma_f32_16x16x32_bf16(af1, bf0, a10, 0, 0, 0);
        a11 = __builtin_amdgcn_mfma_f32_16x16x32_bf16(af1, bf1, a11, 0, 0, 0);
        a12 = __builtin_amdgcn_mfma_f32_16x16x32_bf16(af1, bf2, a12, 0, 0, 0);
        a13 = __builtin_amdgcn_mfma_f32_16x16x32_bf16(af1, bf3, a13, 0, 0, 0);
        a20 = __builtin_amdgcn_mfma_f32_16x16x32_bf16(af2, bf0, a20, 0, 0, 0);
        a21 = __builtin_amdgcn_mfma_f32_16x16x32_bf16(af2, bf1, a21, 0, 0, 0);
        a22 = __builtin_amdgcn_mfma_f32_16x16x32_bf16(af2, bf2, a22, 0, 0, 0);
        a23 = __builtin_amdgcn_mfma_f32_16x16x32_bf16(af2, bf3, a23, 0, 0, 0);
        a30 = __builtin_amdgcn_mfma_f32_16x16x32_bf16(af3, bf0, a30, 0, 0, 0);
        a31 = __builtin_amdgcn_mfma_f32_16x16x32_bf16(af3, bf1, a31, 0, 0, 0);
        a32 = __builtin_amdgcn_mfma_f32_16x16x32_bf16(af3, bf2, a32, 0, 0, 0);
        a33 = __builtin_amdgcn_mfma_f32_16x16x32_bf16(af3, bf3, a33, 0, 0, 0);
    }

    const int colbase = n0 + wn * 64 + l15;

    #define EPIROW(A0, A1, A2, A3, MI)                                         \
    {                                                                          \
        _Pragma("unroll")                                                      \
        for (int r = 0; r < 4; ++r) {                                          \
            const int rloc = wm * 64 + (MI) * 16 + quad * 4 + r;               \
            const int lab = labs[rloc];                                        \
            float part = 0.f;                                                  \
            part += epi_term((A0)[r], colbase,      lab, st, m0 + rloc);       \
            part += epi_term((A1)[r], colbase + 16, lab, st, m0 + rloc);       \
            part += epi_term((A2)[r], colbase + 32, lab, st, m0 + rloc);       \
            part += epi_term((A3)[r], colbase + 48, lab, st, m0 + rloc);       \
            part += __shfl_xor(part, 1);                                       \
            part += __shfl_xor(part, 2);                                       \
            part += __shfl_xor(part, 4);                                       \
            part += __shfl_xor(part, 8);                                       \
            if (l15 == 0) atomicAdd(&rowSum[rloc], part);                      \
        }                                                                      \
    }

    EPIROW(a00, a01, a02, a03, 0)
    EPIROW(a10, a11, a12, a13, 1)
    EPIROW(a20, a21, a22, a23, 2)
    EPIROW(a30, a31, a32, a33, 3)
    #undef EPIROW

    __syncthreads();
    if (tid < BM) partial[(size_t)y * B_BATCH + m0 + tid] = rowSum[tid];
}

// ---------------- kernel 3: per-row combine + mean loss ----------------
__global__ __launch_bounds__(64) void reduce_loss(const float* __restrict__ partial,
                                                  const float* __restrict__ st,
                                                  float* __restrict__ out) {
    const int b = blockIdx.x;
    const int l = threadIdx.x;
    float L = 0.f;
    for (int t = l; t < NTILES; t += 64) L += partial[(size_t)t * B_BATCH + b];
    #pragma unroll
    for (int off = 1; off < 64; off <<= 1) L += __shfl_xor(L, off);
    if (l == 0) {
        float logp = st[b] - 64.0f - logf(L);
        float lossb = fminf(-logp, NEG_LOG_EPS) * (1.0f / (float)B_BATCH);
        atomicAdd(out, lossb);
    }
}

extern "C" void kernel_launch(void* const* d_in, const int* in_sizes, int n_in,
                              void* d_out, int out_size, void* d_ws, size_t ws_size,
                              hipStream_t stream) {
    const float* emb = (const float*)d_in[0];
    const float* wgt = (const float*)d_in[1];
    const int*   lab = (const int*)d_in[2];
    float* out = (float*)d_out;
    char* ws = (char*)d_ws;

    const size_t WBF_B = (size_t)C_CLASSES * D_DIM * 2;  // 102,400,000
    const size_t ABF_B = (size_t)B_BATCH * D_DIM * 2;    // 1,048,576

    unsigned short* Wbf = (unsigned short*)ws;
    unsigned short* Abf = (unsigned short*)(ws + WBF_B);
    float* st      = (float*)(ws + WBF_B + ABF_B);
    float* partial = (float*)(ws + WBF_B + ABF_B + 4096);

    hipMemsetAsync(d_out, 0, sizeof(float), stream);
    norm_embed<<<B_BATCH, 256, 0, stream>>>(emb, Abf);
    norm_weight<<<C_CLASSES / 8, 256, 0, stream>>>(wgt, Wbf);
    gemm_cos<<<GRID_G, 256, 0, stream>>>(Abf, Wbf, lab, st, partial);
    reduce_loss<<<B_BATCH, 64, 0, stream>>>(partial, st, out);
}